// Round 8
// baseline (2285.980 us; speedup 1.0000x reference)
//
#include <hip/hip_runtime.h>
#include <hip/hip_bf16.h>

// ShiftWindAttention on MI355X (gfx950), bf16 MFMA pipeline.
// Round 8: R6 structure exactly (128x256, BK=32 dbuf, 2-phase, vmcnt(2), 0-conflict SWZ)
// with __launch_bounds__(512,6) -> 3 blocks/CU (was 2). Pure occupancy A/B.

typedef __attribute__((ext_vector_type(4))) float f32x4;
typedef __attribute__((ext_vector_type(8))) __bf16 bf16x8;
typedef __attribute__((ext_vector_type(8))) unsigned short u16x8;

__device__ __forceinline__ unsigned short f2bf(float f) {
  __hip_bfloat16 h = __float2bfloat16(f);
  return __builtin_bit_cast(unsigned short, h);
}
__device__ __forceinline__ float bf2f(unsigned short u) {
  return __builtin_bit_cast(float, ((unsigned int)u) << 16);
}

#define GLL16(gsrc, ldst)                                                              \
  __builtin_amdgcn_global_load_lds((const __attribute__((address_space(1))) void*)(gsrc), \
                                   (__attribute__((address_space(3))) void*)(ldst), 16, 0, 0)

// Row-XOR swizzle for 64B rows (involution), measured 0 conflicts in R5-R7:
// toggle 16B-slot bits [5:4] with row bits [2:1] (byte bits [8:7]).
#define SWZ(x) ((x) ^ ((((x) >> 7) & 3) << 4))

#define MFMA_BF16 __builtin_amdgcn_mfma_f32_16x16x32_bf16

// ---------------- conversion kernels ----------------
__global__ __launch_bounds__(256) void cvt_x_kernel(const float* __restrict__ in,
                                                    unsigned short* __restrict__ out, int n4) {
  int i = blockIdx.x * blockDim.x + threadIdx.x;
  int stride = gridDim.x * blockDim.x;
  for (; i < n4; i += stride) {
    float4 v = reinterpret_cast<const float4*>(in)[i];
    ushort4 o;
    o.x = f2bf(v.x); o.y = f2bf(v.y); o.z = f2bf(v.z); o.w = f2bf(v.w);
    reinterpret_cast<ushort4*>(out)[i] = o;
  }
}

__global__ __launch_bounds__(256) void cvt_T_kernel(const float* __restrict__ in,
                                                    unsigned short* __restrict__ out,
                                                    int R, int C) {
  int idx = blockIdx.x * 256 + threadIdx.x;
  if (idx < R * C) {
    int r = idx / C, c = idx - r * C;
    out[(size_t)c * R + r] = f2bf(in[idx]);
  }
}

// ---------------- 128x256 GEMM, BK=32 dbuf: C[M,N] = A[M,K] * B[N,K]^T ----------------
// 512 threads = 8 waves (2M x 4N), per-wave 64x64 out (acc[4][4] = 64 regs).
// LDS: A 2x8K + B 2x16K = 48 KiB -> 3 blocks/CU at launch_bounds(512,6).
template <bool OUT_BF16>
__global__ __launch_bounds__(512, 6) void gemm2p(const unsigned short* __restrict__ A, int lda,
                                                 const unsigned short* __restrict__ B, int ldb,
                                                 void* __restrict__ Cv, int ldc,
                                                 const float* __restrict__ bias, int N, int K) {
  __shared__ alignas(16) unsigned char lds[49152];  // A: [0,16K) 2x8K; B: [16K,48K) 2x16K
  const int tid = threadIdx.x, lane = tid & 63, wave = tid >> 6;
  const int wm = wave >> 2, wn = wave & 3;
  const int nbn = N >> 8;
  const int nwg = gridDim.x;
  const int b0 = blockIdx.x;
  const int sb = (b0 & 7) * (nwg >> 3) + (b0 >> 3);  // bijective: nwg % 8 == 0
  const int bm = sb / nbn, bn = sb - bm * nbn;
  const int m0 = bm << 7, n0 = bn << 8;
  const int nkt = K >> 5;

  // staging: A tile = 128 rows x 64B = 8192 B (1 GLL16/thread);
  //          B tile = 256 rows x 64B = 16384 B (2 GLL16/thread).
  const int d0 = tid * 16;
  const int r0g = d0 >> 6;
  const int c0 = (SWZ(d0) & 63) >> 1;
  const int d1 = d0 + 8192;
  const int r1g = d1 >> 6;
  const int c1 = (SWZ(d1) & 63) >> 1;

  const int fr = lane & 15, fk = lane >> 4;
  const int fkb = fk * 16;  // 16B k-slot within 64B row

  auto STAGE_A = [&](const unsigned short* __restrict__ S, int ld, int kt, int base) {
    GLL16(S + (size_t)(m0 + r0g) * ld + kt * 32 + c0, &lds[base + wave * 1024]);
  };
  auto STAGE_B = [&](const unsigned short* __restrict__ S, int ld, int kt, int base) {
    auto* lb = &lds[base + wave * 1024];
    GLL16(S + (size_t)(n0 + r0g) * ld + kt * 32 + c0, lb);
    GLL16(S + (size_t)(n0 + r1g) * ld + kt * 32 + c1, lb + 8192);
  };
  auto LDA_ = [&](int abuf, int mi) -> bf16x8 {
    const int e = (wm * 64 + mi * 16 + fr) * 64 + fkb;
    return *reinterpret_cast<const bf16x8*>(&lds[abuf + SWZ(e)]);
  };
  auto LDB_ = [&](int bbuf, int ni) -> bf16x8 {
    const int e = (wn * 64 + ni * 16 + fr) * 64 + fkb;
    return *reinterpret_cast<const bf16x8*>(&lds[bbuf + SWZ(e)]);
  };

  // prologue: A(0) [1 load], B(0) [2], B(1) [2]; vmcnt(2) => A(0),B(0) landed, B(1) in flight
  STAGE_A(A, lda, 0, 0);
  STAGE_B(B, ldb, 0, 16384);
  STAGE_B(B, ldb, (nkt > 1) ? 1 : 0, 16384 + 16384);
  asm volatile("s_waitcnt vmcnt(2)" ::: "memory");
  __builtin_amdgcn_s_barrier();

  f32x4 acc[4][4] = {};
  bf16x8 Af[2], Bf[4];

  for (int u = 0; u < nkt; ++u) {
    const int abuf = (u & 1) * 8192;
    const int anx = ((u + 1) & 1) * 8192;
    const int bbuf = 16384 + (u & 1) * 16384;
    const int kA = (u + 1 < nkt) ? u + 1 : nkt - 1;
    const int kB = (u + 2 < nkt) ? u + 2 : nkt - 1;

    // ---- phase 1: read Af m0-1 + Bf n0-3; stage A(u+1); MFMA (m0-1 x n0-3)
    Af[0] = LDA_(abuf, 0);
    Af[1] = LDA_(abuf, 1);
#pragma unroll
    for (int ni = 0; ni < 4; ++ni) Bf[ni] = LDB_(bbuf, ni);
    STAGE_A(A, lda, kA, anx);
    __builtin_amdgcn_s_barrier();
    asm volatile("s_waitcnt lgkmcnt(0)" ::: "memory");
    __builtin_amdgcn_s_setprio(1);
#pragma unroll
    for (int mi = 0; mi < 2; ++mi)
#pragma unroll
      for (int ni = 0; ni < 4; ++ni)
        acc[mi][ni] = MFMA_BF16(Af[mi], Bf[ni], acc[mi][ni], 0, 0, 0);
    __builtin_amdgcn_s_setprio(0);
    __builtin_amdgcn_s_barrier();

    // ---- phase 2: read Af m2-3; stage B(u+2) into bbuf (B reads certified in ph1); vmcnt(2)
    Af[0] = LDA_(abuf, 2);
    Af[1] = LDA_(abuf, 3);
    STAGE_B(B, ldb, kB, bbuf);
    asm volatile("s_waitcnt vmcnt(2)" ::: "memory");
    __builtin_amdgcn_s_barrier();
    asm volatile("s_waitcnt lgkmcnt(0)" ::: "memory");
    __builtin_amdgcn_s_setprio(1);
#pragma unroll
    for (int mi = 0; mi < 2; ++mi)
#pragma unroll
      for (int ni = 0; ni < 4; ++ni)
        acc[2 + mi][ni] = MFMA_BF16(Af[mi], Bf[ni], acc[2 + mi][ni], 0, 0, 0);
    __builtin_amdgcn_s_setprio(0);
    __builtin_amdgcn_s_barrier();
  }

  // epilogue: C/D layout col = lane&15, row = (lane>>4)*4 + r
  const int er = fk << 2;
#pragma unroll
  for (int mi = 0; mi < 4; ++mi)
#pragma unroll
    for (int ni = 0; ni < 4; ++ni) {
      const int col = n0 + wn * 64 + ni * 16 + fr;
#pragma unroll
      for (int r = 0; r < 4; ++r) {
        const size_t row = (size_t)(m0 + wm * 64 + mi * 16 + er + r);
        if (OUT_BF16)
          ((unsigned short*)Cv)[row * ldc + col] = f2bf(acc[mi][ni][r]);
        else
          ((float*)Cv)[row * ldc + col] = acc[mi][ni][r] + bias[col];
      }
    }
}

// ---------------- windowed attention ----------------
__device__ __forceinline__ int region_of(int wy, int wx, int t) {
  int yr = wy * 8 + (t >> 3);
  int xr = wx * 8 + (t & 7);
  int ry = (yr < 24) ? 0 : ((yr < 28) ? 1 : 2);
  int rx = (xr < 24) ? 0 : ((xr < 28) ? 1 : 2);
  return ry * 3 + rx;
}

__global__ __launch_bounds__(256) void win_attn(const unsigned short* __restrict__ qkv,
                                                const float* __restrict__ bias_table,
                                                unsigned short* __restrict__ out,
                                                int nb16) {
  __shared__ alignas(16) unsigned short vt[4][64][72];
  __shared__ alignas(16) unsigned short pl[4][64][72];
  __shared__ unsigned short bias_sh[225 * 16];

  const int tid = threadIdx.x, lane = tid & 63, wave = tid >> 6;
  const int bid = blockIdx.x;
  const int g = bid / nb16;
  const int bw = bid - g * nb16;
  const int b = bw >> 4, w = bw & 15;
  const int wy = w >> 2, wx = w & 3;
  const int shift = g ? 4 : 0;

  for (int i = tid; i < 225 * 16; i += 256) bias_sh[i] = f2bf(bias_table[i]);
  __syncthreads();

  const int r0 = lane & 15, hi4 = lane >> 4;

  for (int hh = 0; hh < 2; ++hh) {
    const int head = g * 8 + wave * 2 + hh;
    const int qcol = head * 64;

    bf16x8 qf[4][2], kf[4][2];
#pragma unroll
    for (int mi = 0; mi < 4; ++mi) {
      const int t = mi * 16 + r0;
      const int y = (wy * 8 + (t >> 3) + shift) & 31;
      const int x = (wx * 8 + (t & 7) + shift) & 31;
      const size_t base = (size_t)((b << 10) + (y << 5) + x) * 3072 + qcol;
#pragma unroll
      for (int kb = 0; kb < 2; ++kb) {
        const int d = kb * 32 + hi4 * 8;
        qf[mi][kb] = *reinterpret_cast<const bf16x8*>(&qkv[base + d]);
        kf[mi][kb] = *reinterpret_cast<const bf16x8*>(&qkv[base + 1024 + d]);
      }
    }

    {
      const int y = (wy * 8 + (lane >> 3) + shift) & 31;
      const int x = (wx * 8 + (lane & 7) + shift) & 31;
      const unsigned short* vsrc =
          qkv + (size_t)((b << 10) + (y << 5) + x) * 3072 + 2048 + qcol;
#pragma unroll
      for (int d0 = 0; d0 < 8; ++d0) {
        u16x8 vv = *reinterpret_cast<const u16x8*>(&vsrc[d0 * 8]);
#pragma unroll
        for (int jj = 0; jj < 8; ++jj) vt[wave][d0 * 8 + jj][lane] = vv[jj];
      }
    }

    f32x4 s[4][4] = {};
#pragma unroll
    for (int mi = 0; mi < 4; ++mi)
#pragma unroll
      for (int ni = 0; ni < 4; ++ni) {
        s[mi][ni] = MFMA_BF16(qf[mi][0], kf[ni][0], s[mi][ni], 0, 0, 0);
        s[mi][ni] = MFMA_BF16(qf[mi][1], kf[ni][1], s[mi][ni], 0, 0, 0);
      }

    int rj[4];
#pragma unroll
    for (int ni = 0; ni < 4; ++ni) rj[ni] = region_of(wy, wx, ni * 16 + r0);
    float rinv[4][4];
#pragma unroll
    for (int mi = 0; mi < 4; ++mi) {
#pragma unroll
      for (int r = 0; r < 4; ++r) {
        const int it = mi * 16 + hi4 * 4 + r;
        const int iy = it >> 3, ix = it & 7;
        const int ri = region_of(wy, wx, it);
        float vals[4], vmax = -1e30f;
#pragma unroll
        for (int ni = 0; ni < 4; ++ni) {
          const int jt = ni * 16 + r0;
          const int ridx = (iy - (jt >> 3) + 7) * 15 + (ix - (jt & 7) + 7);
          float v = s[mi][ni][r] * 0.125f + bf2f(bias_sh[ridx * 16 + head]);
          if (g && ri != rj[ni]) v = -1e9f;
          vals[ni] = v;
          vmax = fmaxf(vmax, v);
        }
        vmax = fmaxf(vmax, __shfl_xor(vmax, 1));
        vmax = fmaxf(vmax, __shfl_xor(vmax, 2));
        vmax = fmaxf(vmax, __shfl_xor(vmax, 4));
        vmax = fmaxf(vmax, __shfl_xor(vmax, 8));
        float ssum = 0.f;
#pragma unroll
        for (int ni = 0; ni < 4; ++ni) {
          float p = __expf(vals[ni] - vmax);
          ssum += p;
          s[mi][ni][r] = p;
        }
        ssum += __shfl_xor(ssum, 1);
        ssum += __shfl_xor(ssum, 2);
        ssum += __shfl_xor(ssum, 4);
        ssum += __shfl_xor(ssum, 8);
        rinv[mi][r] = 1.0f / ssum;
      }
    }

#pragma unroll
    for (int mi = 0; mi < 4; ++mi)
#pragma unroll
      for (int ni = 0; ni < 4; ++ni)
#pragma unroll
        for (int r = 0; r < 4; ++r)
          pl[wave][mi * 16 + hi4 * 4 + r][ni * 16 + r0] = f2bf(s[mi][ni][r]);

    f32x4 o[4][4] = {};
#pragma unroll
    for (int kb = 0; kb < 2; ++kb) {
      bf16x8 pf[4], vf[4];
#pragma unroll
      for (int mi = 0; mi < 4; ++mi)
        pf[mi] = *reinterpret_cast<const bf16x8*>(&pl[wave][mi * 16 + r0][kb * 32 + hi4 * 8]);
#pragma unroll
      for (int di = 0; di < 4; ++di)
        vf[di] = *reinterpret_cast<const bf16x8*>(&vt[wave][di * 16 + r0][kb * 32 + hi4 * 8]);
#pragma unroll
      for (int mi = 0; mi < 4; ++mi)
#pragma unroll
        for (int di = 0; di < 4; ++di)
          o[mi][di] = MFMA_BF16(pf[mi], vf[di], o[mi][di], 0, 0, 0);
    }

#pragma unroll
    for (int mi = 0; mi < 4; ++mi)
#pragma unroll
      for (int r = 0; r < 4; ++r) {
        const int it = mi * 16 + hi4 * 4 + r;
        const int y = (wy * 8 + (it >> 3) + shift) & 31;
        const int x = (wx * 8 + (it & 7) + shift) & 31;
        unsigned short* op = out + (size_t)((b << 10) + (y << 5) + x) * 3072 + head * 64;
        const float rv = rinv[mi][r];
#pragma unroll
        for (int di = 0; di < 4; ++di) op[di * 16 + r0] = f2bf(o[mi][di][r] * rv);
      }
  }
}

// ---------------- launcher ----------------
extern "C" void kernel_launch(void* const* d_in, const int* in_sizes, int n_in,
                              void* d_out, int out_size, void* d_ws, size_t ws_size,
                              hipStream_t stream) {
  const float* x = (const float*)d_in[0];
  const float* w_qkv = (const float*)d_in[1];
  const float* bias_table = (const float*)d_in[2];
  const float* w_out = (const float*)d_in[3];
  const float* b_out = (const float*)d_in[4];
  float* out = (float*)d_out;

  int S = 1;
  for (; S < 16; S <<= 1) {
    size_t need = 2ull * (2097152ull + 234881024ull / (size_t)S);
    if (need <= ws_size) break;
  }
  const int Mc = 65536 / S;
  const int nb = 64 / S;

  unsigned short* wqt = (unsigned short*)d_ws;
  unsigned short* wot = wqt + (size_t)1572864;
  unsigned short* xb  = wot + (size_t)524288;
  unsigned short* qkv = xb + (size_t)Mc * 512;

  cvt_T_kernel<<<6144, 256, 0, stream>>>(w_qkv, wqt, 512, 3072);
  cvt_T_kernel<<<2048, 256, 0, stream>>>(w_out, wot, 1024, 512);

  for (int c = 0; c < S; ++c) {
    const float* xc = x + (size_t)c * Mc * 512;
    cvt_x_kernel<<<2048, 256, 0, stream>>>(xc, xb, Mc * 128);
    gemm2p<true><<<(Mc >> 7) * 12, 512, 0, stream>>>(xb, 512, wqt, 512, (void*)qkv, 3072,
                                                     nullptr, 3072, 512);
    win_attn<<<2 * nb * 16, 256, 0, stream>>>(qkv, bias_table, qkv, nb * 16);
    gemm2p<false><<<(Mc >> 7) * 2, 512, 0, stream>>>(qkv, 3072, wot, 1024,
                                                     (void*)(out + (size_t)c * Mc * 512), 512,
                                                     b_out, 512, 1024);
  }
}

// Round 9
// 668.272 us; speedup vs baseline: 3.4207x; 3.4207x over previous
//
#include <hip/hip_runtime.h>
#include <hip/hip_bf16.h>

// ShiftWindAttention on MI355X (gfx950), bf16 MFMA pipeline.
// Round 9: gemm back to proven (512,4) R6 structure; cvt_x FUSED into gemm1
// (A read as fp32, reg-staged cvt -> swizzled ds_write); win_attn LDS stride
// 72->70 (2 blocks/CU + ~2-way banks).

typedef __attribute__((ext_vector_type(4))) float f32x4;
typedef __attribute__((ext_vector_type(8))) __bf16 bf16x8;
typedef __attribute__((ext_vector_type(8))) unsigned short u16x8;

__device__ __forceinline__ unsigned short f2bf(float f) {
  __hip_bfloat16 h = __float2bfloat16(f);
  return __builtin_bit_cast(unsigned short, h);
}
__device__ __forceinline__ float bf2f(unsigned short u) {
  return __builtin_bit_cast(float, ((unsigned int)u) << 16);
}

#define GLL16(gsrc, ldst)                                                              \
  __builtin_amdgcn_global_load_lds((const __attribute__((address_space(1))) void*)(gsrc), \
                                   (__attribute__((address_space(3))) void*)(ldst), 16, 0, 0)

// Row-XOR swizzle for 64B rows (involution), measured 0 conflicts in R5-R8:
// toggle 16B-slot bits [5:4] with row bits [2:1] (byte bits [8:7]).
#define SWZ(x) ((x) ^ ((((x) >> 7) & 3) << 4))

#define MFMA_BF16 __builtin_amdgcn_mfma_f32_16x16x32_bf16

// ---------------- conversion kernel (weights only) ----------------
__global__ __launch_bounds__(256) void cvt_T_kernel(const float* __restrict__ in,
                                                    unsigned short* __restrict__ out,
                                                    int R, int C) {
  int idx = blockIdx.x * 256 + threadIdx.x;
  if (idx < R * C) {
    int r = idx / C, c = idx - r * C;
    out[(size_t)c * R + r] = f2bf(in[idx]);
  }
}

// ---------------- 128x256 GEMM, BK=32 dbuf: C[M,N] = A[M,K] * B[N,K]^T ----------------
// 512 threads = 8 waves (2M x 4N), per-wave 64x64 out (acc[4][4] = 64 regs).
// LDS: A 2x8K + B 2x16K = 48 KiB, 2 blocks/CU at (512,4).
// QKV mode: A is fp32 (x), reg-staged (load->cvt->swizzled ds_write); out bf16, no bias.
// else:     A is bf16 via global_load_lds; out f32 + bias.
template <bool QKV>
__global__ __launch_bounds__(512, 4) void gemm2p(const void* __restrict__ Av, int lda,
                                                 const unsigned short* __restrict__ B, int ldb,
                                                 void* __restrict__ Cv, int ldc,
                                                 const float* __restrict__ bias, int N, int K) {
  __shared__ alignas(16) unsigned char lds[49152];  // A: [0,16K) 2x8K; B: [16K,48K) 2x16K
  const int tid = threadIdx.x, lane = tid & 63, wave = tid >> 6;
  const int wm = wave >> 2, wn = wave & 3;
  const int nbn = N >> 8;
  const int nwg = gridDim.x;
  const int b0 = blockIdx.x;
  const int sb = (b0 & 7) * (nwg >> 3) + (b0 >> 3);  // bijective: nwg % 8 == 0
  const int bm = sb / nbn, bn = sb - bm * nbn;
  const int m0 = bm << 7, n0 = bn << 8;
  const int nkt = K >> 5;

  const float* Af32 = (const float*)Av;
  const unsigned short* Ab16 = (const unsigned short*)Av;

  // staging geometry (byte offset within an 8KB half / 16KB tile): d0 = tid*16
  const int d0 = tid * 16;
  const int r0g = d0 >> 6;
  const int c0 = (SWZ(d0) & 63) >> 1;
  const int d1 = d0 + 8192;
  const int r1g = d1 >> 6;
  const int c1 = (SWZ(d1) & 63) >> 1;
  const int swzd = SWZ(d0);                    // A ds_write dest (QKV mode)
  const int arow = tid >> 2, acol = (tid & 3) * 8;  // fp32 A-load geometry

  const int fr = lane & 15, fk = lane >> 4;
  const int fkb = fk * 16;  // 16B k-slot within 64B row

  auto STAGE_A16 = [&](int kt, int base) {
    GLL16(Ab16 + (size_t)(m0 + r0g) * lda + kt * 32 + c0, &lds[base + wave * 1024]);
  };
  auto STAGE_B = [&](int kt, int base) {
    auto* lb = &lds[base + wave * 1024];
    GLL16(B + (size_t)(n0 + r0g) * ldb + kt * 32 + c0, lb);
    GLL16(B + (size_t)(n0 + r1g) * ldb + kt * 32 + c1, lb + 8192);
  };
  auto LOAD_A32 = [&](int kt, f32x4& g0, f32x4& g1) {
    const float* ap = Af32 + (size_t)(m0 + arow) * lda + kt * 32 + acol;
    g0 = *reinterpret_cast<const f32x4*>(ap);
    g1 = *reinterpret_cast<const f32x4*>(ap + 4);
  };
  auto WRA = [&](int abase, const f32x4& g0, const f32x4& g1) {
    u16x8 h;
#pragma unroll
    for (int j = 0; j < 4; ++j) { h[j] = f2bf(g0[j]); h[j + 4] = f2bf(g1[j]); }
    *reinterpret_cast<u16x8*>(&lds[abase + swzd]) = h;
  };
  auto LDA_ = [&](int abuf, int mi) -> bf16x8 {
    const int e = (wm * 64 + mi * 16 + fr) * 64 + fkb;
    return *reinterpret_cast<const bf16x8*>(&lds[abuf + SWZ(e)]);
  };
  auto LDB_ = [&](int bbuf, int ni) -> bf16x8 {
    const int e = (wn * 64 + ni * 16 + fr) * 64 + fkb;
    return *reinterpret_cast<const bf16x8*>(&lds[bbuf + SWZ(e)]);
  };

  // ---- prologue ----
  f32x4 g0, g1;
  if constexpr (QKV) {
    LOAD_A32(0, g0, g1);                       // 2 reg loads
  } else {
    STAGE_A16(0, 0);                           // 1 GLL
  }
  STAGE_B(0, 16384);                           // 2 GLL
  STAGE_B((nkt > 1) ? 1 : 0, 16384 + 16384);   // 2 GLL
  if constexpr (QKV) {
    asm volatile("s_waitcnt vmcnt(4)" ::: "memory");  // A-reg loads done
    WRA(0, g0, g1);
    asm volatile("s_waitcnt vmcnt(2)" ::: "memory");  // B(0) done, B(1) in flight
    asm volatile("s_waitcnt lgkmcnt(0)" ::: "memory");  // A0 write visible
  } else {
    asm volatile("s_waitcnt vmcnt(2)" ::: "memory");  // A(0),B(0) done, B(1) in flight
  }
  __builtin_amdgcn_s_barrier();

  f32x4 acc[4][4] = {};
  bf16x8 Af[2], Bf[4];

  for (int u = 0; u < nkt; ++u) {
    const int abuf = (u & 1) * 8192;
    const int anx = ((u + 1) & 1) * 8192;
    const int bbuf = 16384 + (u & 1) * 16384;
    const int kA = (u + 1 < nkt) ? u + 1 : nkt - 1;
    const int kB = (u + 2 < nkt) ? u + 2 : nkt - 1;

    // ---- phase 1: A(u+1) issue; read Af m0-1 + Bf n0-3; MFMA (m0-1 x n0-3)
    if constexpr (QKV) {
      LOAD_A32(kA, g0, g1);
    }
    Af[0] = LDA_(abuf, 0);
    Af[1] = LDA_(abuf, 1);
#pragma unroll
    for (int ni = 0; ni < 4; ++ni) Bf[ni] = LDB_(bbuf, ni);
    if constexpr (!QKV) STAGE_A16(kA, anx);
    __builtin_amdgcn_s_barrier();
    asm volatile("s_waitcnt lgkmcnt(0)" ::: "memory");
    __builtin_amdgcn_s_setprio(1);
#pragma unroll
    for (int mi = 0; mi < 2; ++mi)
#pragma unroll
      for (int ni = 0; ni < 4; ++ni)
        acc[mi][ni] = MFMA_BF16(Af[mi], Bf[ni], acc[mi][ni], 0, 0, 0);
    __builtin_amdgcn_s_setprio(0);
    __builtin_amdgcn_s_barrier();

    // ---- phase 2: read Af m2-3; stage B(u+2); vmcnt(2) certifies tile u+1; write A(u+1)
    Af[0] = LDA_(abuf, 2);
    Af[1] = LDA_(abuf, 3);
    STAGE_B(kB, bbuf);
    asm volatile("s_waitcnt vmcnt(2)" ::: "memory");
    if constexpr (QKV) {
      WRA(anx, g0, g1);  // certified by lgkmcnt(0) below, before trailing barrier
    }
    __builtin_amdgcn_s_barrier();
    asm volatile("s_waitcnt lgkmcnt(0)" ::: "memory");
    __builtin_amdgcn_s_setprio(1);
#pragma unroll
    for (int mi = 0; mi < 2; ++mi)
#pragma unroll
      for (int ni = 0; ni < 4; ++ni)
        acc[2 + mi][ni] = MFMA_BF16(Af[mi], Bf[ni], acc[2 + mi][ni], 0, 0, 0);
    __builtin_amdgcn_s_setprio(0);
    __builtin_amdgcn_s_barrier();
  }

  // epilogue: C/D layout col = lane&15, row = (lane>>4)*4 + r
  const int er = fk << 2;
#pragma unroll
  for (int mi = 0; mi < 4; ++mi)
#pragma unroll
    for (int ni = 0; ni < 4; ++ni) {
      const int col = n0 + wn * 64 + ni * 16 + fr;
#pragma unroll
      for (int r = 0; r < 4; ++r) {
        const size_t row = (size_t)(m0 + wm * 64 + mi * 16 + er + r);
        if (QKV)
          ((unsigned short*)Cv)[row * ldc + col] = f2bf(acc[mi][ni][r]);
        else
          ((float*)Cv)[row * ldc + col] = acc[mi][ni][r] + bias[col];
      }
    }
}

// ---------------- windowed attention ----------------
__device__ __forceinline__ int region_of(int wy, int wx, int t) {
  int yr = wy * 8 + (t >> 3);
  int xr = wx * 8 + (t & 7);
  int ry = (yr < 24) ? 0 : ((yr < 28) ? 1 : 2);
  int rx = (xr < 24) ? 0 : ((xr < 28) ? 1 : 2);
  return ry * 3 + rx;
}

__global__ __launch_bounds__(256) void win_attn(const unsigned short* __restrict__ qkv,
                                                const float* __restrict__ bias_table,
                                                unsigned short* __restrict__ out,
                                                int nb16) {
  __shared__ alignas(16) unsigned short vt[4][64][70];  // stride 140B: ~2-way banks; 2 blk/CU
  __shared__ alignas(16) unsigned short pl[4][64][70];
  __shared__ unsigned short bias_sh[225 * 16];

  const int tid = threadIdx.x, lane = tid & 63, wave = tid >> 6;
  const int bid = blockIdx.x;
  const int g = bid / nb16;
  const int bw = bid - g * nb16;
  const int b = bw >> 4, w = bw & 15;
  const int wy = w >> 2, wx = w & 3;
  const int shift = g ? 4 : 0;

  for (int i = tid; i < 225 * 16; i += 256) bias_sh[i] = f2bf(bias_table[i]);
  __syncthreads();

  const int r0 = lane & 15, hi4 = lane >> 4;

  for (int hh = 0; hh < 2; ++hh) {
    const int head = g * 8 + wave * 2 + hh;
    const int qcol = head * 64;

    bf16x8 qf[4][2], kf[4][2];
#pragma unroll
    for (int mi = 0; mi < 4; ++mi) {
      const int t = mi * 16 + r0;
      const int y = (wy * 8 + (t >> 3) + shift) & 31;
      const int x = (wx * 8 + (t & 7) + shift) & 31;
      const size_t base = (size_t)((b << 10) + (y << 5) + x) * 3072 + qcol;
#pragma unroll
      for (int kb = 0; kb < 2; ++kb) {
        const int d = kb * 32 + hi4 * 8;
        qf[mi][kb] = *reinterpret_cast<const bf16x8*>(&qkv[base + d]);
        kf[mi][kb] = *reinterpret_cast<const bf16x8*>(&qkv[base + 1024 + d]);
      }
    }

    {
      const int y = (wy * 8 + (lane >> 3) + shift) & 31;
      const int x = (wx * 8 + (lane & 7) + shift) & 31;
      const unsigned short* vsrc =
          qkv + (size_t)((b << 10) + (y << 5) + x) * 3072 + 2048 + qcol;
#pragma unroll
      for (int d0 = 0; d0 < 8; ++d0) {
        u16x8 vv = *reinterpret_cast<const u16x8*>(&vsrc[d0 * 8]);
#pragma unroll
        for (int jj = 0; jj < 8; ++jj) vt[wave][d0 * 8 + jj][lane] = vv[jj];
      }
    }

    f32x4 s[4][4] = {};
#pragma unroll
    for (int mi = 0; mi < 4; ++mi)
#pragma unroll
      for (int ni = 0; ni < 4; ++ni) {
        s[mi][ni] = MFMA_BF16(qf[mi][0], kf[ni][0], s[mi][ni], 0, 0, 0);
        s[mi][ni] = MFMA_BF16(qf[mi][1], kf[ni][1], s[mi][ni], 0, 0, 0);
      }

    int rj[4];
#pragma unroll
    for (int ni = 0; ni < 4; ++ni) rj[ni] = region_of(wy, wx, ni * 16 + r0);
    float rinv[4][4];
#pragma unroll
    for (int mi = 0; mi < 4; ++mi) {
#pragma unroll
      for (int r = 0; r < 4; ++r) {
        const int it = mi * 16 + hi4 * 4 + r;
        const int iy = it >> 3, ix = it & 7;
        const int ri = region_of(wy, wx, it);
        float vals[4], vmax = -1e30f;
#pragma unroll
        for (int ni = 0; ni < 4; ++ni) {
          const int jt = ni * 16 + r0;
          const int ridx = (iy - (jt >> 3) + 7) * 15 + (ix - (jt & 7) + 7);
          float v = s[mi][ni][r] * 0.125f + bf2f(bias_sh[ridx * 16 + head]);
          if (g && ri != rj[ni]) v = -1e9f;
          vals[ni] = v;
          vmax = fmaxf(vmax, v);
        }
        vmax = fmaxf(vmax, __shfl_xor(vmax, 1));
        vmax = fmaxf(vmax, __shfl_xor(vmax, 2));
        vmax = fmaxf(vmax, __shfl_xor(vmax, 4));
        vmax = fmaxf(vmax, __shfl_xor(vmax, 8));
        float ssum = 0.f;
#pragma unroll
        for (int ni = 0; ni < 4; ++ni) {
          float p = __expf(vals[ni] - vmax);
          ssum += p;
          s[mi][ni][r] = p;
        }
        ssum += __shfl_xor(ssum, 1);
        ssum += __shfl_xor(ssum, 2);
        ssum += __shfl_xor(ssum, 4);
        ssum += __shfl_xor(ssum, 8);
        rinv[mi][r] = 1.0f / ssum;
      }
    }

#pragma unroll
    for (int mi = 0; mi < 4; ++mi)
#pragma unroll
      for (int ni = 0; ni < 4; ++ni)
#pragma unroll
        for (int r = 0; r < 4; ++r)
          pl[wave][mi * 16 + hi4 * 4 + r][ni * 16 + r0] = f2bf(s[mi][ni][r]);

    f32x4 o[4][4] = {};
#pragma unroll
    for (int kb = 0; kb < 2; ++kb) {
      bf16x8 pf[4], vf[4];
#pragma unroll
      for (int mi = 0; mi < 4; ++mi)
        pf[mi] = *reinterpret_cast<const bf16x8*>(&pl[wave][mi * 16 + r0][kb * 32 + hi4 * 8]);
#pragma unroll
      for (int di = 0; di < 4; ++di)
        vf[di] = *reinterpret_cast<const bf16x8*>(&vt[wave][di * 16 + r0][kb * 32 + hi4 * 8]);
#pragma unroll
      for (int mi = 0; mi < 4; ++mi)
#pragma unroll
        for (int di = 0; di < 4; ++di)
          o[mi][di] = MFMA_BF16(pf[mi], vf[di], o[mi][di], 0, 0, 0);
    }

#pragma unroll
    for (int mi = 0; mi < 4; ++mi)
#pragma unroll
      for (int r = 0; r < 4; ++r) {
        const int it = mi * 16 + hi4 * 4 + r;
        const int y = (wy * 8 + (it >> 3) + shift) & 31;
        const int x = (wx * 8 + (it & 7) + shift) & 31;
        unsigned short* op = out + (size_t)((b << 10) + (y << 5) + x) * 3072 + head * 64;
        const float rv = rinv[mi][r];
#pragma unroll
        for (int di = 0; di < 4; ++di) op[di * 16 + r0] = f2bf(o[mi][di][r] * rv);
      }
  }
}

// ---------------- launcher ----------------
extern "C" void kernel_launch(void* const* d_in, const int* in_sizes, int n_in,
                              void* d_out, int out_size, void* d_ws, size_t ws_size,
                              hipStream_t stream) {
  const float* x = (const float*)d_in[0];
  const float* w_qkv = (const float*)d_in[1];
  const float* bias_table = (const float*)d_in[2];
  const float* w_out = (const float*)d_in[3];
  const float* b_out = (const float*)d_in[4];
  float* out = (float*)d_out;

  int S = 1;
  for (; S < 16; S <<= 1) {
    size_t need = 4194304ull + 402653184ull / (size_t)S;
    if (need <= ws_size) break;
  }
  const int Mc = 65536 / S;
  const int nb = 64 / S;

  unsigned short* wqt = (unsigned short*)d_ws;
  unsigned short* wot = wqt + (size_t)1572864;
  unsigned short* qkv = wot + (size_t)524288;

  cvt_T_kernel<<<6144, 256, 0, stream>>>(w_qkv, wqt, 512, 3072);
  cvt_T_kernel<<<2048, 256, 0, stream>>>(w_out, wot, 1024, 512);

  for (int c = 0; c < S; ++c) {
    const float* xc = x + (size_t)c * Mc * 512;
    gemm2p<true><<<(Mc >> 7) * 12, 512, 0, stream>>>((const void*)xc, 512, wqt, 512,
                                                     (void*)qkv, 3072, nullptr, 3072, 512);
    win_attn<<<2 * nb * 16, 256, 0, stream>>>(qkv, bias_table, qkv, nb * 16);
    gemm2p<false><<<(Mc >> 7) * 2, 512, 0, stream>>>((const void*)qkv, 3072, wot, 1024,
                                                     (void*)(out + (size_t)c * Mc * 512), 512,
                                                     b_out, 512, 1024);
  }
}

// Round 10
// 593.132 us; speedup vs baseline: 3.8541x; 1.1267x over previous
//
#include <hip/hip_runtime.h>
#include <hip/hip_bf16.h>

// ShiftWindAttention on MI355X (gfx950), bf16 MFMA pipeline.
// Round 10: gemm/cvt = R6-exact (proven gemm1 268us). win_attn LDS 80.9->75.3KB
// (8-head bias LUT, pl stride 68) -> 2 blocks/CU for latency hiding.

typedef __attribute__((ext_vector_type(4))) float f32x4;
typedef __attribute__((ext_vector_type(8))) __bf16 bf16x8;
typedef __attribute__((ext_vector_type(8))) unsigned short u16x8;

__device__ __forceinline__ unsigned short f2bf(float f) {
  __hip_bfloat16 h = __float2bfloat16(f);
  return __builtin_bit_cast(unsigned short, h);
}
__device__ __forceinline__ float bf2f(unsigned short u) {
  return __builtin_bit_cast(float, ((unsigned int)u) << 16);
}

#define GLL16(gsrc, ldst)                                                              \
  __builtin_amdgcn_global_load_lds((const __attribute__((address_space(1))) void*)(gsrc), \
                                   (__attribute__((address_space(3))) void*)(ldst), 16, 0, 0)

// Row-XOR swizzle for 64B rows (involution), measured 0 conflicts in R5-R9:
// toggle 16B-slot bits [5:4] with row bits [2:1] (byte bits [8:7]).
#define SWZ(x) ((x) ^ ((((x) >> 7) & 3) << 4))

#define MFMA_BF16 __builtin_amdgcn_mfma_f32_16x16x32_bf16

// ---------------- conversion kernels ----------------
__global__ __launch_bounds__(256) void cvt_x_kernel(const float* __restrict__ in,
                                                    unsigned short* __restrict__ out, int n4) {
  int i = blockIdx.x * blockDim.x + threadIdx.x;
  int stride = gridDim.x * blockDim.x;
  for (; i < n4; i += stride) {
    float4 v = reinterpret_cast<const float4*>(in)[i];
    ushort4 o;
    o.x = f2bf(v.x); o.y = f2bf(v.y); o.z = f2bf(v.z); o.w = f2bf(v.w);
    reinterpret_cast<ushort4*>(out)[i] = o;
  }
}

__global__ __launch_bounds__(256) void cvt_T_kernel(const float* __restrict__ in,
                                                    unsigned short* __restrict__ out,
                                                    int R, int C) {
  int idx = blockIdx.x * 256 + threadIdx.x;
  if (idx < R * C) {
    int r = idx / C, c = idx - r * C;
    out[(size_t)c * R + r] = f2bf(in[idx]);
  }
}

// ---------------- 128x256 GEMM, BK=32 dbuf: C[M,N] = A[M,K] * B[N,K]^T ----------------
// 512 threads = 8 waves (2M x 4N), per-wave 64x64 out (acc[4][4] = 64 regs).
// LDS: A 2x8K + B 2x16K = 48 KiB, 2 blocks/CU at (512,4).  [R6-proven: 268us]
template <bool OUT_BF16>
__global__ __launch_bounds__(512, 4) void gemm2p(const unsigned short* __restrict__ A, int lda,
                                                 const unsigned short* __restrict__ B, int ldb,
                                                 void* __restrict__ Cv, int ldc,
                                                 const float* __restrict__ bias, int N, int K) {
  __shared__ alignas(16) unsigned char lds[49152];  // A: [0,16K) 2x8K; B: [16K,48K) 2x16K
  const int tid = threadIdx.x, lane = tid & 63, wave = tid >> 6;
  const int wm = wave >> 2, wn = wave & 3;
  const int nbn = N >> 8;
  const int nwg = gridDim.x;
  const int b0 = blockIdx.x;
  const int sb = (b0 & 7) * (nwg >> 3) + (b0 >> 3);  // bijective: nwg % 8 == 0
  const int bm = sb / nbn, bn = sb - bm * nbn;
  const int m0 = bm << 7, n0 = bn << 8;
  const int nkt = K >> 5;

  const int d0 = tid * 16;
  const int r0g = d0 >> 6;
  const int c0 = (SWZ(d0) & 63) >> 1;
  const int d1 = d0 + 8192;
  const int r1g = d1 >> 6;
  const int c1 = (SWZ(d1) & 63) >> 1;

  const int fr = lane & 15, fk = lane >> 4;
  const int fkb = fk * 16;  // 16B k-slot within 64B row

  auto STAGE_A = [&](const unsigned short* __restrict__ S, int ld, int kt, int base) {
    GLL16(S + (size_t)(m0 + r0g) * ld + kt * 32 + c0, &lds[base + wave * 1024]);
  };
  auto STAGE_B = [&](const unsigned short* __restrict__ S, int ld, int kt, int base) {
    auto* lb = &lds[base + wave * 1024];
    GLL16(S + (size_t)(n0 + r0g) * ld + kt * 32 + c0, lb);
    GLL16(S + (size_t)(n0 + r1g) * ld + kt * 32 + c1, lb + 8192);
  };
  auto LDA_ = [&](int abuf, int mi) -> bf16x8 {
    const int e = (wm * 64 + mi * 16 + fr) * 64 + fkb;
    return *reinterpret_cast<const bf16x8*>(&lds[abuf + SWZ(e)]);
  };
  auto LDB_ = [&](int bbuf, int ni) -> bf16x8 {
    const int e = (wn * 64 + ni * 16 + fr) * 64 + fkb;
    return *reinterpret_cast<const bf16x8*>(&lds[bbuf + SWZ(e)]);
  };

  // prologue: A(0) [1 load], B(0) [2], B(1) [2]; vmcnt(2) => A(0),B(0) landed, B(1) in flight
  STAGE_A(A, lda, 0, 0);
  STAGE_B(B, ldb, 0, 16384);
  STAGE_B(B, ldb, (nkt > 1) ? 1 : 0, 16384 + 16384);
  asm volatile("s_waitcnt vmcnt(2)" ::: "memory");
  __builtin_amdgcn_s_barrier();

  f32x4 acc[4][4] = {};
  bf16x8 Af[2], Bf[4];

  for (int u = 0; u < nkt; ++u) {
    const int abuf = (u & 1) * 8192;
    const int anx = ((u + 1) & 1) * 8192;
    const int bbuf = 16384 + (u & 1) * 16384;
    const int kA = (u + 1 < nkt) ? u + 1 : nkt - 1;
    const int kB = (u + 2 < nkt) ? u + 2 : nkt - 1;

    // ---- phase 1: read Af m0-1 + Bf n0-3; stage A(u+1); MFMA (m0-1 x n0-3)
    Af[0] = LDA_(abuf, 0);
    Af[1] = LDA_(abuf, 1);
#pragma unroll
    for (int ni = 0; ni < 4; ++ni) Bf[ni] = LDB_(bbuf, ni);
    STAGE_A(A, lda, kA, anx);
    __builtin_amdgcn_s_barrier();
    asm volatile("s_waitcnt lgkmcnt(0)" ::: "memory");
    __builtin_amdgcn_s_setprio(1);
#pragma unroll
    for (int mi = 0; mi < 2; ++mi)
#pragma unroll
      for (int ni = 0; ni < 4; ++ni)
        acc[mi][ni] = MFMA_BF16(Af[mi], Bf[ni], acc[mi][ni], 0, 0, 0);
    __builtin_amdgcn_s_setprio(0);
    __builtin_amdgcn_s_barrier();

    // ---- phase 2: read Af m2-3; stage B(u+2) into bbuf (B reads certified in ph1); vmcnt(2)
    Af[0] = LDA_(abuf, 2);
    Af[1] = LDA_(abuf, 3);
    STAGE_B(B, ldb, kB, bbuf);
    asm volatile("s_waitcnt vmcnt(2)" ::: "memory");
    __builtin_amdgcn_s_barrier();
    asm volatile("s_waitcnt lgkmcnt(0)" ::: "memory");
    __builtin_amdgcn_s_setprio(1);
#pragma unroll
    for (int mi = 0; mi < 2; ++mi)
#pragma unroll
      for (int ni = 0; ni < 4; ++ni)
        acc[2 + mi][ni] = MFMA_BF16(Af[mi], Bf[ni], acc[2 + mi][ni], 0, 0, 0);
    __builtin_amdgcn_s_setprio(0);
    __builtin_amdgcn_s_barrier();
  }

  // epilogue: C/D layout col = lane&15, row = (lane>>4)*4 + r
  const int er = fk << 2;
#pragma unroll
  for (int mi = 0; mi < 4; ++mi)
#pragma unroll
    for (int ni = 0; ni < 4; ++ni) {
      const int col = n0 + wn * 64 + ni * 16 + fr;
#pragma unroll
      for (int r = 0; r < 4; ++r) {
        const size_t row = (size_t)(m0 + wm * 64 + mi * 16 + er + r);
        if (OUT_BF16)
          ((unsigned short*)Cv)[row * ldc + col] = f2bf(acc[mi][ni][r]);
        else
          ((float*)Cv)[row * ldc + col] = acc[mi][ni][r] + bias[col];
      }
    }
}

// ---------------- windowed attention ----------------
__device__ __forceinline__ int region_of(int wy, int wx, int t) {
  int yr = wy * 8 + (t >> 3);
  int xr = wx * 8 + (t & 7);
  int ry = (yr < 24) ? 0 : ((yr < 28) ? 1 : 2);
  int rx = (xr < 24) ? 0 : ((xr < 28) ? 1 : 2);
  return ry * 3 + rx;
}

// LDS: vt 4*64*72*2 = 36864 + pl 4*64*68*2 = 34816 + bias 225*8*2 = 3600 -> 75280 B
// => 2 blocks/CU (was 80928 -> 1 block/CU).
__global__ __launch_bounds__(256) void win_attn(const unsigned short* __restrict__ qkv,
                                                const float* __restrict__ bias_table,
                                                unsigned short* __restrict__ out,
                                                int nb16) {
  __shared__ alignas(16) unsigned short vt[4][64][72];
  __shared__ alignas(16) unsigned short pl[4][64][68];
  __shared__ unsigned short bias_sh[225 * 8];

  const int tid = threadIdx.x, lane = tid & 63, wave = tid >> 6;
  const int bid = blockIdx.x;
  const int g = bid / nb16;
  const int bw = bid - g * nb16;
  const int b = bw >> 4, w = bw & 15;
  const int wy = w >> 2, wx = w & 3;
  const int shift = g ? 4 : 0;

  // bias LUT: only this group's 8 heads
  for (int i = tid; i < 225 * 8; i += 256)
    bias_sh[i] = f2bf(bias_table[(i >> 3) * 16 + g * 8 + (i & 7)]);
  __syncthreads();

  const int r0 = lane & 15, hi4 = lane >> 4;

  for (int hh = 0; hh < 2; ++hh) {
    const int hloc = wave * 2 + hh;       // head within group (0..7)
    const int head = g * 8 + hloc;
    const int qcol = head * 64;

    bf16x8 qf[4][2], kf[4][2];
#pragma unroll
    for (int mi = 0; mi < 4; ++mi) {
      const int t = mi * 16 + r0;
      const int y = (wy * 8 + (t >> 3) + shift) & 31;
      const int x = (wx * 8 + (t & 7) + shift) & 31;
      const size_t base = (size_t)((b << 10) + (y << 5) + x) * 3072 + qcol;
#pragma unroll
      for (int kb = 0; kb < 2; ++kb) {
        const int d = kb * 32 + hi4 * 8;
        qf[mi][kb] = *reinterpret_cast<const bf16x8*>(&qkv[base + d]);
        kf[mi][kb] = *reinterpret_cast<const bf16x8*>(&qkv[base + 1024 + d]);
      }
    }

    {
      const int y = (wy * 8 + (lane >> 3) + shift) & 31;
      const int x = (wx * 8 + (lane & 7) + shift) & 31;
      const unsigned short* vsrc =
          qkv + (size_t)((b << 10) + (y << 5) + x) * 3072 + 2048 + qcol;
#pragma unroll
      for (int d0 = 0; d0 < 8; ++d0) {
        u16x8 vv = *reinterpret_cast<const u16x8*>(&vsrc[d0 * 8]);
#pragma unroll
        for (int jj = 0; jj < 8; ++jj) vt[wave][d0 * 8 + jj][lane] = vv[jj];
      }
    }

    f32x4 s[4][4] = {};
#pragma unroll
    for (int mi = 0; mi < 4; ++mi)
#pragma unroll
      for (int ni = 0; ni < 4; ++ni) {
        s[mi][ni] = MFMA_BF16(qf[mi][0], kf[ni][0], s[mi][ni], 0, 0, 0);
        s[mi][ni] = MFMA_BF16(qf[mi][1], kf[ni][1], s[mi][ni], 0, 0, 0);
      }

    int rj[4];
#pragma unroll
    for (int ni = 0; ni < 4; ++ni) rj[ni] = region_of(wy, wx, ni * 16 + r0);
    float rinv[4][4];
#pragma unroll
    for (int mi = 0; mi < 4; ++mi) {
#pragma unroll
      for (int r = 0; r < 4; ++r) {
        const int it = mi * 16 + hi4 * 4 + r;
        const int iy = it >> 3, ix = it & 7;
        const int ri = region_of(wy, wx, it);
        float vals[4], vmax = -1e30f;
#pragma unroll
        for (int ni = 0; ni < 4; ++ni) {
          const int jt = ni * 16 + r0;
          const int ridx = (iy - (jt >> 3) + 7) * 15 + (ix - (jt & 7) + 7);
          float v = s[mi][ni][r] * 0.125f + bf2f(bias_sh[ridx * 8 + hloc]);
          if (g && ri != rj[ni]) v = -1e9f;
          vals[ni] = v;
          vmax = fmaxf(vmax, v);
        }
        vmax = fmaxf(vmax, __shfl_xor(vmax, 1));
        vmax = fmaxf(vmax, __shfl_xor(vmax, 2));
        vmax = fmaxf(vmax, __shfl_xor(vmax, 4));
        vmax = fmaxf(vmax, __shfl_xor(vmax, 8));
        float ssum = 0.f;
#pragma unroll
        for (int ni = 0; ni < 4; ++ni) {
          float p = __expf(vals[ni] - vmax);
          ssum += p;
          s[mi][ni][r] = p;
        }
        ssum += __shfl_xor(ssum, 1);
        ssum += __shfl_xor(ssum, 2);
        ssum += __shfl_xor(ssum, 4);
        ssum += __shfl_xor(ssum, 8);
        rinv[mi][r] = 1.0f / ssum;
      }
    }

#pragma unroll
    for (int mi = 0; mi < 4; ++mi)
#pragma unroll
      for (int ni = 0; ni < 4; ++ni)
#pragma unroll
        for (int r = 0; r < 4; ++r)
          pl[wave][mi * 16 + hi4 * 4 + r][ni * 16 + r0] = f2bf(s[mi][ni][r]);

    f32x4 o[4][4] = {};
#pragma unroll
    for (int kb = 0; kb < 2; ++kb) {
      bf16x8 pf[4], vf[4];
#pragma unroll
      for (int mi = 0; mi < 4; ++mi)
        pf[mi] = *reinterpret_cast<const bf16x8*>(&pl[wave][mi * 16 + r0][kb * 32 + hi4 * 8]);
#pragma unroll
      for (int di = 0; di < 4; ++di)
        vf[di] = *reinterpret_cast<const bf16x8*>(&vt[wave][di * 16 + r0][kb * 32 + hi4 * 8]);
#pragma unroll
      for (int mi = 0; mi < 4; ++mi)
#pragma unroll
        for (int di = 0; di < 4; ++di)
          o[mi][di] = MFMA_BF16(pf[mi], vf[di], o[mi][di], 0, 0, 0);
    }

#pragma unroll
    for (int mi = 0; mi < 4; ++mi)
#pragma unroll
      for (int r = 0; r < 4; ++r) {
        const int it = mi * 16 + hi4 * 4 + r;
        const int y = (wy * 8 + (it >> 3) + shift) & 31;
        const int x = (wx * 8 + (it & 7) + shift) & 31;
        unsigned short* op = out + (size_t)((b << 10) + (y << 5) + x) * 3072 + head * 64;
        const float rv = rinv[mi][r];
#pragma unroll
        for (int di = 0; di < 4; ++di) op[di * 16 + r0] = f2bf(o[mi][di][r] * rv);
      }
  }
}

// ---------------- launcher ----------------
extern "C" void kernel_launch(void* const* d_in, const int* in_sizes, int n_in,
                              void* d_out, int out_size, void* d_ws, size_t ws_size,
                              hipStream_t stream) {
  const float* x = (const float*)d_in[0];
  const float* w_qkv = (const float*)d_in[1];
  const float* bias_table = (const float*)d_in[2];
  const float* w_out = (const float*)d_in[3];
  const float* b_out = (const float*)d_in[4];
  float* out = (float*)d_out;

  int S = 1;
  for (; S < 16; S <<= 1) {
    size_t need = 2ull * (2097152ull + 234881024ull / (size_t)S);
    if (need <= ws_size) break;
  }
  const int Mc = 65536 / S;
  const int nb = 64 / S;

  unsigned short* wqt = (unsigned short*)d_ws;
  unsigned short* wot = wqt + (size_t)1572864;
  unsigned short* xb  = wot + (size_t)524288;
  unsigned short* qkv = xb + (size_t)Mc * 512;

  cvt_T_kernel<<<6144, 256, 0, stream>>>(w_qkv, wqt, 512, 3072);
  cvt_T_kernel<<<2048, 256, 0, stream>>>(w_out, wot, 1024, 512);

  for (int c = 0; c < S; ++c) {
    const float* xc = x + (size_t)c * Mc * 512;
    cvt_x_kernel<<<2048, 256, 0, stream>>>(xc, xb, Mc * 128);
    gemm2p<true><<<(Mc >> 7) * 12, 512, 0, stream>>>(xb, 512, wqt, 512, (void*)qkv, 3072,
                                                     nullptr, 3072, 512);
    win_attn<<<2 * nb * 16, 256, 0, stream>>>(qkv, bias_table, qkv, nb * 16);
    gemm2p<false><<<(Mc >> 7) * 2, 512, 0, stream>>>(qkv, 3072, wot, 1024,
                                                     (void*)(out + (size_t)c * Mc * 512), 512,
                                                     b_out, 512, 1024);
  }
}